// Round 1
// baseline (250.404 us; speedup 1.0000x reference)
//
#include <hip/hip_runtime.h>

// Hopf oscillator scan.
// Shapes: X_r, X_i: [bs=8, T=64, d=32, d=32, nk=32] fp32; omegas: [32,32,32].
// Outputs: (r*cos(phi), r*sin(phi)) each [8,64,32,32,32], concatenated in d_out.
// 262,144 independent chains over the (bs, d, d, nk) axes; T is sequential.

#define T_STEPS 64
#define CH      32768            // d*d*nk — innermost contiguous channel block
#define BS      8

__global__ __launch_bounds__(256)
void hopf_scan_kernel(const float2* __restrict__ Xr,
                      const float2* __restrict__ Xi,
                      const float2* __restrict__ Om,
                      float2* __restrict__ out)
{
    const float DT = 0.01f;
    const float SC = 20.0f;

    int tid = blockIdx.x * blockDim.x + threadIdx.x;   // 0 .. 131071
    int b   = tid >> 14;            // 16384 float2-pairs per batch (32768 ch / 2)
    int cp  = tid & 16383;          // pair index inside the channel block

    float2 omega = Om[cp];

    const size_t stride = CH / 2;                       // float2 stride per t
    size_t base = (size_t)(b * T_STEPS) * stride + cp;
    const float2* pxr = Xr + base;
    const float2* pxi = Xi + base;
    float2* po0 = out + base;
    float2* po1 = po0 + (size_t)BS * T_STEPS * stride;  // second output tensor

    // carry: r, phi, and cos/sin of current phi (phi0 = 0)
    float r0 = 1.f, r1 = 1.f;
    float ph0 = 0.f, ph1 = 0.f;
    float c0 = 1.f, s0 = 0.f, c1 = 1.f, s1 = 0.f;

    #pragma unroll 4
    for (int t = 0; t < T_STEPS; ++t) {
        float2 xr = pxr[(size_t)t * stride];
        float2 xi = pxi[(size_t)t * stride];

        // channel 0
        float ir = SC * xr.x * c0;                // uses OLD phi's cos
        float ip = SC * xi.x * s0;                // uses OLD phi's sin
        r0  = r0  + ((1.f - r0 * r0) * r0 + ir) * DT;
        ph0 = ph0 + (omega.x - ip) * DT;
        sincosf(ph0, &s0, &c0);                   // precise OCML sincos

        // channel 1
        float jr = SC * xr.y * c1;
        float jp = SC * xi.y * s1;
        r1  = r1  + ((1.f - r1 * r1) * r1 + jr) * DT;
        ph1 = ph1 + (omega.y - jp) * DT;
        sincosf(ph1, &s1, &c1);

        po0[(size_t)t * stride] = make_float2(r0 * c0, r1 * c1);
        po1[(size_t)t * stride] = make_float2(r0 * s0, r1 * s1);
    }
}

extern "C" void kernel_launch(void* const* d_in, const int* in_sizes, int n_in,
                              void* d_out, int out_size, void* d_ws, size_t ws_size,
                              hipStream_t stream) {
    const float2* Xr = (const float2*)d_in[0];
    const float2* Xi = (const float2*)d_in[1];
    const float2* Om = (const float2*)d_in[2];
    float2* out = (float2*)d_out;

    // 8 * 32768 channels / 2 per thread = 131072 threads
    dim3 block(256);
    dim3 grid((BS * CH / 2) / 256);   // 512 blocks
    hopf_scan_kernel<<<grid, block, 0, stream>>>(Xr, Xi, Om, out);
}

// Round 2
// 239.059 us; speedup vs baseline: 1.0475x; 1.0475x over previous
//
#include <hip/hip_runtime.h>

// Hopf oscillator scan.
// X_r, X_i: [bs=8, T=64, d=32, d=32, nk=32] fp32; omegas: [32,32,32].
// Outputs: (r*cos(phi), r*sin(phi)) each [8,64,32,32,32], concatenated.
// 262,144 independent chains over (bs,d,d,nk); T sequential.
// R2: 1 channel/thread (4096 waves, 16/CU), prefetch depth 4, nt stores.

#define T_STEPS 64
#define CH      32768
#define BS      8
#define PF      4

__global__ __launch_bounds__(256)
void hopf_scan_kernel(const float* __restrict__ Xr,
                      const float* __restrict__ Xi,
                      const float* __restrict__ Om,
                      float* __restrict__ out)
{
    const float DT = 0.01f;
    const float SC = 20.0f;

    int tid = blockIdx.x * blockDim.x + threadIdx.x;   // 0 .. 262143
    int b   = tid >> 15;                               // batch index
    int c   = tid & (CH - 1);                          // channel in [0,32768)

    float omega = Om[c];

    const size_t stride = CH;                          // float stride per t
    size_t base = (size_t)(b * T_STEPS) * stride + c;
    const float* pxr = Xr + base;
    const float* pxi = Xi + base;
    float* po0 = out + base;
    float* po1 = po0 + (size_t)BS * T_STEPS * stride;  // second output tensor

    // carry: r, phi, cos/sin of current phi (phi0 = 0 -> c=1, s=0)
    float r = 1.f, ph = 0.f, co = 1.f, si = 0.f;

    // prime the pipeline: loads for t = 0..PF-1
    float xr[PF], xi[PF];
    #pragma unroll
    for (int i = 0; i < PF; ++i) {
        xr[i] = pxr[(size_t)i * stride];
        xi[i] = pxi[(size_t)i * stride];
    }

    for (int t0 = 0; t0 < T_STEPS; t0 += PF) {
        // issue next block's loads first — keeps 8 loads in flight
        float nxr[PF], nxi[PF];
        if (t0 + PF < T_STEPS) {
            #pragma unroll
            for (int i = 0; i < PF; ++i) {
                nxr[i] = pxr[(size_t)(t0 + PF + i) * stride];
                nxi[i] = pxi[(size_t)(t0 + PF + i) * stride];
            }
        }

        #pragma unroll
        for (int i = 0; i < PF; ++i) {
            float ir = SC * xr[i] * co;           // OLD phi's cos
            float ip = SC * xi[i] * si;           // OLD phi's sin
            r  = r  + ((1.f - r * r) * r + ir) * DT;
            ph = ph + (omega - ip) * DT;
            sincosf(ph, &si, &co);                // precise OCML sincos
            size_t off = (size_t)(t0 + i) * stride;
            __builtin_nontemporal_store(r * co, po0 + off);
            __builtin_nontemporal_store(r * si, po1 + off);
        }

        #pragma unroll
        for (int i = 0; i < PF; ++i) { xr[i] = nxr[i]; xi[i] = nxi[i]; }
    }
}

extern "C" void kernel_launch(void* const* d_in, const int* in_sizes, int n_in,
                              void* d_out, int out_size, void* d_ws, size_t ws_size,
                              hipStream_t stream) {
    const float* Xr = (const float*)d_in[0];
    const float* Xi = (const float*)d_in[1];
    const float* Om = (const float*)d_in[2];
    float* out = (float*)d_out;

    dim3 block(256);
    dim3 grid(BS * CH / 256);   // 1024 blocks = 262144 threads
    hopf_scan_kernel<<<grid, block, 0, stream>>>(Xr, Xi, Om, out);
}

// Round 3
// 236.086 us; speedup vs baseline: 1.0606x; 1.0126x over previous
//
#include <hip/hip_runtime.h>

// Hopf oscillator scan.
// X_r, X_i: [bs=8, T=64, d=32, d=32, nk=32] fp32; omegas: [32,32,32].
// Outputs: (r*cos(phi), r*sin(phi)) each [8,64,32,32,32], concatenated.
// 262,144 independent chains over (bs,d,d,nk); T sequential.
// R3: replace OCML sincosf (serial ~100cy, ~95 inst/step) with unit-vector
//     rotation by small angle dphi via Taylor sin/cos (deg 9/8, err < 2.5e-8
//     at |dphi|=1). phi itself is never needed — only (cos,sin).

#define T_STEPS 64
#define CH      32768
#define BS      8
#define PF      4

__global__ __launch_bounds__(256)
void hopf_scan_kernel(const float* __restrict__ Xr,
                      const float* __restrict__ Xi,
                      const float* __restrict__ Om,
                      float* __restrict__ out)
{
    const float DT = 0.01f;
    const float SC = 20.0f;
    // Taylor coeffs: sin(x) = x*(1 + u*(S1 + u*(S2 + u*(S3 + u*S4)))), u=x^2
    const float S1 = -1.6666667e-1f, S2 = 8.3333333e-3f,
                S3 = -1.9841270e-4f, S4 = 2.7557319e-6f;
    // cos(x) = 1 + u*(C1 + u*(C2 + u*(C3 + u*C4)))
    const float C1 = -0.5f, C2 = 4.1666667e-2f,
                C3 = -1.3888889e-3f, C4 = 2.4801587e-5f;

    int tid = blockIdx.x * blockDim.x + threadIdx.x;   // 0 .. 262143
    int b   = tid >> 15;
    int c   = tid & (CH - 1);

    float omega = Om[c];

    const size_t stride = CH;
    size_t base = (size_t)(b * T_STEPS) * stride + c;
    const float* pxr = Xr + base;
    const float* pxi = Xi + base;
    float* po0 = out + base;
    float* po1 = po0 + (size_t)BS * T_STEPS * stride;

    float r = 1.f, co = 1.f, si = 0.f;                 // phi0 = 0

    float xr[PF], xi[PF];
    #pragma unroll
    for (int i = 0; i < PF; ++i) {
        xr[i] = pxr[(size_t)i * stride];
        xi[i] = pxi[(size_t)i * stride];
    }

    for (int t0 = 0; t0 < T_STEPS; t0 += PF) {
        float nxr[PF], nxi[PF];
        if (t0 + PF < T_STEPS) {
            #pragma unroll
            for (int i = 0; i < PF; ++i) {
                nxr[i] = pxr[(size_t)(t0 + PF + i) * stride];
                nxi[i] = pxi[(size_t)(t0 + PF + i) * stride];
            }
        }

        #pragma unroll
        for (int i = 0; i < PF; ++i) {
            float ir   = SC * xr[i] * co;                      // old cos
            float dphi = (omega - SC * xi[i] * si) * DT;       // old sin
            r = r + ((1.f - r * r) * r + ir) * DT;             // off trig chain

            float u  = dphi * dphi;
            float sp = fmaf(u, S4, S3);
            sp = fmaf(u, sp, S2);
            sp = fmaf(u, sp, S1);
            sp = fmaf(u, sp, 1.f);
            sp *= dphi;                                        // sin(dphi)
            float cp = fmaf(u, C4, C3);
            cp = fmaf(u, cp, C2);
            cp = fmaf(u, cp, C1);
            cp = fmaf(u, cp, 1.f);                             // cos(dphi)

            float nco = fmaf(co, cp, -si * sp);                // rotate
            float nsi = fmaf(si, cp,  co * sp);
            co = nco; si = nsi;

            size_t off = (size_t)(t0 + i) * stride;
            __builtin_nontemporal_store(r * co, po0 + off);
            __builtin_nontemporal_store(r * si, po1 + off);
        }

        #pragma unroll
        for (int i = 0; i < PF; ++i) { xr[i] = nxr[i]; xi[i] = nxi[i]; }
    }
}

extern "C" void kernel_launch(void* const* d_in, const int* in_sizes, int n_in,
                              void* d_out, int out_size, void* d_ws, size_t ws_size,
                              hipStream_t stream) {
    const float* Xr = (const float*)d_in[0];
    const float* Xi = (const float*)d_in[1];
    const float* Om = (const float*)d_in[2];
    float* out = (float*)d_out;

    dim3 block(256);
    dim3 grid(BS * CH / 256);   // 1024 blocks = 262144 threads
    hopf_scan_kernel<<<grid, block, 0, stream>>>(Xr, Xi, Om, out);
}

// Round 4
// 234.749 us; speedup vs baseline: 1.0667x; 1.0057x over previous
//
#include <hip/hip_runtime.h>

// Hopf oscillator scan.
// X_r, X_i: [bs=8, T=64, d=32, d=32, nk=32] fp32; omegas: [32,32,32].
// Outputs: (r*cos(phi), r*sin(phi)) each [8,64,32,32,32], concatenated.
// 262,144 independent chains over (bs,d,d,nk); T sequential.
// R4: depth-16 register software pipeline (32 loads in flight per wave,
//     ~33 MB device-wide MLP) to break the Little's-law ceiling that pinned
//     R1-R3 at 2.4 TB/s (8.4 MB in flight / ~3.5 us loaded latency).
//     Trig via small-angle rotation (R3). Full unroll of T=64.

#define T_STEPS 64
#define CH      32768
#define BS      8
#define DEPTH   16            // pipeline depth in t-steps (2 loads per step)

__global__ __launch_bounds__(256)
void hopf_scan_kernel(const float* __restrict__ Xr,
                      const float* __restrict__ Xi,
                      const float* __restrict__ Om,
                      float* __restrict__ out)
{
    const float DT = 0.01f;
    const float SC = 20.0f;
    // sin(x) = x*(1 + u*(S1 + u*(S2 + u*(S3 + u*S4)))), u = x^2
    const float S1 = -1.6666667e-1f, S2 = 8.3333333e-3f,
                S3 = -1.9841270e-4f, S4 = 2.7557319e-6f;
    // cos(x) = 1 + u*(C1 + u*(C2 + u*(C3 + u*C4)))
    const float C1 = -0.5f, C2 = 4.1666667e-2f,
                C3 = -1.3888889e-3f, C4 = 2.4801587e-5f;

    int tid = blockIdx.x * blockDim.x + threadIdx.x;   // 0 .. 262143
    int b   = tid >> 15;
    int c   = tid & (CH - 1);

    float omega = Om[c];

    const size_t stride = CH;
    size_t base = (size_t)(b * T_STEPS) * stride + c;
    const float* pxr = Xr + base;
    const float* pxi = Xi + base;
    float* po0 = out + base;
    float* po1 = po0 + (size_t)BS * T_STEPS * stride;

    float r = 1.f, co = 1.f, si = 0.f;                 // phi0 = 0

    // prime: loads for t = 0..DEPTH-1 (32 loads in flight)
    float xr[DEPTH], xi[DEPTH];
    #pragma unroll
    for (int i = 0; i < DEPTH; ++i) {
        xr[i] = pxr[(size_t)i * stride];
        xi[i] = pxi[(size_t)i * stride];
    }

    #pragma unroll
    for (int t = 0; t < T_STEPS; ++t) {
        const int s = t & (DEPTH - 1);                 // static after unroll
        float axr = xr[s];
        float axi = xi[s];
        // refill the slot immediately: load for t+DEPTH goes in flight now,
        // consumed DEPTH steps later -> ~32 outstanding loads per wave.
        if (t + DEPTH < T_STEPS) {
            xr[s] = pxr[(size_t)(t + DEPTH) * stride];
            xi[s] = pxi[(size_t)(t + DEPTH) * stride];
        }

        float ir   = SC * axr * co;                    // old cos
        float dphi = (omega - SC * axi * si) * DT;     // old sin
        r = r + ((1.f - r * r) * r + ir) * DT;

        float u  = dphi * dphi;
        float sp = fmaf(u, S4, S3);
        sp = fmaf(u, sp, S2);
        sp = fmaf(u, sp, S1);
        sp = fmaf(u, sp, 1.f);
        sp *= dphi;                                    // sin(dphi)
        float cp = fmaf(u, C4, C3);
        cp = fmaf(u, cp, C2);
        cp = fmaf(u, cp, C1);
        cp = fmaf(u, cp, 1.f);                         // cos(dphi)

        float nco = fmaf(co, cp, -si * sp);
        float nsi = fmaf(si, cp,  co * sp);
        co = nco; si = nsi;

        size_t off = (size_t)t * stride;
        __builtin_nontemporal_store(r * co, po0 + off);
        __builtin_nontemporal_store(r * si, po1 + off);
    }
}

extern "C" void kernel_launch(void* const* d_in, const int* in_sizes, int n_in,
                              void* d_out, int out_size, void* d_ws, size_t ws_size,
                              hipStream_t stream) {
    const float* Xr = (const float*)d_in[0];
    const float* Xi = (const float*)d_in[1];
    const float* Om = (const float*)d_in[2];
    float* out = (float*)d_out;

    dim3 block(256);
    dim3 grid(BS * CH / 256);   // 1024 blocks = 262144 threads
    hopf_scan_kernel<<<grid, block, 0, stream>>>(Xr, Xi, Om, out);
}